// Round 5
// baseline (343.757 us; speedup 1.0000x reference)
//
#include <hip/hip_runtime.h>
#include <hip/hip_cooperative_groups.h>

namespace cg = cooperative_groups;

#define CH 256
#define KK 4
#define PLANE 4096      // 64*64
#define TS 67           // LDS tile row stride (66 cols + 1 pad)
#define PPB 16          // planes per block (fused kernel)

typedef float fx4 __attribute__((ext_vector_type(4)));

// ==================== Fused cooperative kernel ====================
__global__ __launch_bounds__(256, 2) void fused_kernel(
    const float* __restrict__ x, const float* __restrict__ conv_w,
    const float* __restrict__ fc1_w, const float* __restrict__ fc1_b,
    const float* __restrict__ fc2_w, const float* __restrict__ fc2_b,
    float* __restrict__ g, float* __restrict__ out)
{
    __shared__ float tile[66 * TS];   // ~17.7 KiB
    __shared__ float gs[CH];
    __shared__ float hbuf[64];
    __shared__ float logits[KK];
    __shared__ float attn_s[KK];

    int t    = threadIdx.x;
    int lane = t & 63, wid = t >> 6;
    int p0   = blockIdx.x * PPB;      // first plane; all PPB in one batch (16 | 256)

    // ---- Phase 1: GAP. Each wave reduces 4 whole planes (no LDS, no syncs) ----
    for (int j = 0; j < 4; ++j) {
        int plane = p0 + wid * 4 + j;
        const float4* p = (const float4*)(x + (size_t)plane * PLANE);
        float sum = 0.f;
        #pragma unroll
        for (int k = 0; k < 16; ++k) {
            float4 v = p[lane + k * 64];
            sum += (v.x + v.y) + (v.z + v.w);
        }
        for (int off = 32; off > 0; off >>= 1)
            sum += __shfl_down(sum, off);
        if (lane == 0) g[plane] = sum * (1.f / PLANE);
    }

    cg::this_grid().sync();           // g fully written grid-wide

    // ---- Phase 2: attention MLP for this block's batch (redundant per block) ----
    int b = p0 >> 8;
    gs[t] = g[b * CH + t];
    __syncthreads();
    if (t < 64) {
        const float4* wr = (const float4*)(fc1_w + t * CH);
        const float4* gv = (const float4*)gs;
        float a0 = fc1_b[t], a1 = 0.f, a2 = 0.f, a3 = 0.f;
        #pragma unroll 4
        for (int i = 0; i < CH / 4; ++i) {
            float4 w4 = wr[i], g4 = gv[i];
            a0 = fmaf(w4.x, g4.x, a0);
            a1 = fmaf(w4.y, g4.y, a1);
            a2 = fmaf(w4.z, g4.z, a2);
            a3 = fmaf(w4.w, g4.w, a3);
        }
        hbuf[t] = fmaxf((a0 + a1) + (a2 + a3), 0.f);
    }
    __syncthreads();
    if (t < KK) {
        const float4* w2 = (const float4*)(fc2_w + t * 64);
        const float4* hv = (const float4*)hbuf;
        float a0 = fc2_b[t], a1 = 0.f, a2 = 0.f, a3 = 0.f;
        #pragma unroll
        for (int i = 0; i < 16; ++i) {
            float4 w4 = w2[i], h4 = hv[i];
            a0 = fmaf(w4.x, h4.x, a0);
            a1 = fmaf(w4.y, h4.y, a1);
            a2 = fmaf(w4.z, h4.z, a2);
            a3 = fmaf(w4.w, h4.w, a3);
        }
        logits[t] = (a0 + a1) + (a2 + a3);
    }
    __syncthreads();
    if (t == 0) {
        float m = fmaxf(fmaxf(logits[0], logits[1]), fmaxf(logits[2], logits[3]));
        float e0 = __expf(logits[0] - m), e1 = __expf(logits[1] - m),
              e2 = __expf(logits[2] - m), e3 = __expf(logits[3] - m);
        float inv = 1.f / (e0 + e1 + e2 + e3);
        attn_s[0] = e0 * inv; attn_s[1] = e1 * inv;
        attn_s[2] = e2 * inv; attn_s[3] = e3 * inv;
    }

    // ---- zero tile halo once (interior-only staging preserves it) ----
    for (int i = t; i < 260; i += 256) {
        int idx;
        if (i < 66)       idx = i;
        else if (i < 132) idx = 65 * TS + (i - 66);
        else if (i < 196) idx = (i - 131) * TS;
        else              idx = (i - 195) * TS + 65;
        tile[idx] = 0.f;
    }
    __syncthreads();

    float a0 = attn_s[0], a1 = attn_s[1], a2 = attn_s[2], a3 = attn_s[3];

    // ---- Phase 3: conv for PPB planes (x re-read, L3-resident) ----
    for (int j = 0; j < PPB; ++j) {
        int plane = p0 + j;
        int c = plane & (CH - 1);

        float w[9];
        #pragma unroll
        for (int jj = 0; jj < 9; ++jj) {
            w[jj] = a0 * conv_w[(0 * CH + c) * 9 + jj]
                  + a1 * conv_w[(1 * CH + c) * 9 + jj]
                  + a2 * conv_w[(2 * CH + c) * 9 + jj]
                  + a3 * conv_w[(3 * CH + c) * 9 + jj];
        }

        const float4* xp4 = (const float4*)(x + (size_t)plane * PLANE);
        #pragma unroll
        for (int k = 0; k < 4; ++k) {
            int idx = t + k * 256;
            int y   = idx >> 4;
            int xq  = (idx & 15) << 2;
            float4 v = xp4[idx];
            float* d = &tile[(y + 1) * TS + 1 + xq];
            d[0] = v.x; d[1] = v.y; d[2] = v.z; d[3] = v.w;
        }
        __syncthreads();

        int y0 = t >> 4;
        int xq = (t & 15) << 2;
        fx4* op4 = (fx4*)(out + (size_t)plane * PLANE);
        #pragma unroll
        for (int gi = 0; gi < 4; ++gi) {
            int y = y0 + gi * 16;
            float s0 = 0.f, s1 = 0.f, s2 = 0.f, s3 = 0.f;
            #pragma unroll
            for (int dy = 0; dy < 3; ++dy) {
                const float* r = &tile[(y + dy) * TS + xq];
                float e0 = r[0], e1 = r[1], e2 = r[2], e3 = r[3], e4 = r[4], e5 = r[5];
                float w0 = w[dy * 3], w1 = w[dy * 3 + 1], w2 = w[dy * 3 + 2];
                s0 = fmaf(e0, w0, fmaf(e1, w1, fmaf(e2, w2, s0)));
                s1 = fmaf(e1, w0, fmaf(e2, w1, fmaf(e3, w2, s1)));
                s2 = fmaf(e2, w0, fmaf(e3, w1, fmaf(e4, w2, s2)));
                s3 = fmaf(e3, w0, fmaf(e4, w1, fmaf(e5, w2, s3)));
            }
            fx4 res = {s0, s1, s2, s3};
            __builtin_nontemporal_store(res, &op4[(y << 4) + (t & 15)]);
        }
        __syncthreads();
    }
}

// ==================== Fallback kernels (proven R3 path) ====================
__global__ __launch_bounds__(256) void gap_kernel(const float* __restrict__ x,
                                                  float* __restrict__ g) {
    int plane = blockIdx.x;
    const float4* p = (const float4*)(x + (size_t)plane * PLANE);
    float sum = 0.f;
    #pragma unroll
    for (int k = 0; k < 4; ++k) {
        float4 v = p[threadIdx.x + k * 256];
        sum += (v.x + v.y) + (v.z + v.w);
    }
    for (int off = 32; off > 0; off >>= 1)
        sum += __shfl_down(sum, off);
    __shared__ float ws[4];
    int lane = threadIdx.x & 63;
    int wid  = threadIdx.x >> 6;
    if (lane == 0) ws[wid] = sum;
    __syncthreads();
    if (threadIdx.x == 0)
        g[plane] = (ws[0] + ws[1] + ws[2] + ws[3]) * (1.f / PLANE);
}

__global__ __launch_bounds__(64) void attn_kernel(const float* __restrict__ g,
                            const float* __restrict__ fc1_w, const float* __restrict__ fc1_b,
                            const float* __restrict__ fc2_w, const float* __restrict__ fc2_b,
                            float* __restrict__ attn) {
    int b = blockIdx.x;
    int t = threadIdx.x;
    __shared__ float gs[CH];
    __shared__ float h[64];
    __shared__ float logit[KK];
    for (int i = t; i < CH; i += 64) gs[i] = g[b * CH + i];
    __syncthreads();
    {
        const float4* wr = (const float4*)(fc1_w + t * CH);
        const float4* gv = (const float4*)gs;
        float a0 = fc1_b[t], a1 = 0.f, a2 = 0.f, a3 = 0.f;
        #pragma unroll 4
        for (int i = 0; i < CH / 4; ++i) {
            float4 w4 = wr[i], g4 = gv[i];
            a0 = fmaf(w4.x, g4.x, a0);
            a1 = fmaf(w4.y, g4.y, a1);
            a2 = fmaf(w4.z, g4.z, a2);
            a3 = fmaf(w4.w, g4.w, a3);
        }
        h[t] = fmaxf((a0 + a1) + (a2 + a3), 0.f);
    }
    __syncthreads();
    if (t < KK) {
        const float4* w2 = (const float4*)(fc2_w + t * 64);
        const float4* hv = (const float4*)h;
        float a0 = fc2_b[t], a1 = 0.f, a2 = 0.f, a3 = 0.f;
        #pragma unroll
        for (int i = 0; i < 16; ++i) {
            float4 w4 = w2[i], h4 = hv[i];
            a0 = fmaf(w4.x, h4.x, a0);
            a1 = fmaf(w4.y, h4.y, a1);
            a2 = fmaf(w4.z, h4.z, a2);
            a3 = fmaf(w4.w, h4.w, a3);
        }
        logit[t] = (a0 + a1) + (a2 + a3);
    }
    __syncthreads();
    if (t == 0) {
        float m = fmaxf(fmaxf(logit[0], logit[1]), fmaxf(logit[2], logit[3]));
        float e[KK];
        float s = 0.f;
        #pragma unroll
        for (int k = 0; k < KK; ++k) { e[k] = __expf(logit[k] - m); s += e[k]; }
        float inv = 1.f / s;
        #pragma unroll
        for (int k = 0; k < KK; ++k) attn[b * KK + k] = e[k] * inv;
    }
}

__global__ __launch_bounds__(256) void dwconv_kernel(const float* __restrict__ x,
                              const float* __restrict__ conv_w,
                              const float* __restrict__ attn, float* __restrict__ out) {
    int plane = blockIdx.x;
    int b = plane >> 8;
    int c = plane & (CH - 1);
    __shared__ float tile[66 * TS];
    int t = threadIdx.x;

    for (int i = t; i < 260; i += 256) {
        int idx;
        if (i < 66)       idx = i;
        else if (i < 132) idx = 65 * TS + (i - 66);
        else if (i < 196) idx = (i - 131) * TS;
        else              idx = (i - 195) * TS + 65;
        tile[idx] = 0.f;
    }

    const float4* xp4 = (const float4*)(x + (size_t)plane * PLANE);
    #pragma unroll
    for (int k = 0; k < 4; ++k) {
        int idx = t + k * 256;
        int y   = idx >> 4;
        int xq  = (idx & 15) << 2;
        float4 v = xp4[idx];
        float* d = &tile[(y + 1) * TS + 1 + xq];
        d[0] = v.x; d[1] = v.y; d[2] = v.z; d[3] = v.w;
    }

    float a0 = attn[b * KK + 0], a1 = attn[b * KK + 1],
          a2 = attn[b * KK + 2], a3 = attn[b * KK + 3];
    float w[9];
    #pragma unroll
    for (int j = 0; j < 9; ++j) {
        w[j] = a0 * conv_w[(0 * CH + c) * 9 + j]
             + a1 * conv_w[(1 * CH + c) * 9 + j]
             + a2 * conv_w[(2 * CH + c) * 9 + j]
             + a3 * conv_w[(3 * CH + c) * 9 + j];
    }
    __syncthreads();

    int y0 = t >> 4;
    int xq = (t & 15) << 2;
    fx4* op4 = (fx4*)(out + (size_t)plane * PLANE);
    #pragma unroll
    for (int gi = 0; gi < 4; ++gi) {
        int y = y0 + gi * 16;
        float s0 = 0.f, s1 = 0.f, s2 = 0.f, s3 = 0.f;
        #pragma unroll
        for (int dy = 0; dy < 3; ++dy) {
            const float* r = &tile[(y + dy) * TS + xq];
            float e0 = r[0], e1 = r[1], e2 = r[2], e3 = r[3], e4 = r[4], e5 = r[5];
            float w0 = w[dy * 3], w1 = w[dy * 3 + 1], w2 = w[dy * 3 + 2];
            s0 = fmaf(e0, w0, fmaf(e1, w1, fmaf(e2, w2, s0)));
            s1 = fmaf(e1, w0, fmaf(e2, w1, fmaf(e3, w2, s1)));
            s2 = fmaf(e2, w0, fmaf(e3, w1, fmaf(e4, w2, s2)));
            s3 = fmaf(e3, w0, fmaf(e4, w1, fmaf(e5, w2, s3)));
        }
        fx4 res = {s0, s1, s2, s3};
        __builtin_nontemporal_store(res, &op4[(y << 4) + (t & 15)]);
    }
}

extern "C" void kernel_launch(void* const* d_in, const int* in_sizes, int n_in,
                              void* d_out, int out_size, void* d_ws, size_t ws_size,
                              hipStream_t stream) {
    const float* x      = (const float*)d_in[0];
    const float* conv_w = (const float*)d_in[1];
    const float* fc1_w  = (const float*)d_in[2];
    const float* fc1_b  = (const float*)d_in[3];
    const float* fc2_w  = (const float*)d_in[4];
    const float* fc2_b  = (const float*)d_in[5];
    float* out  = (float*)d_out;
    float* g    = (float*)d_ws;                   // B*CH floats
    float* attn = g + 32 * CH;                    // B*KK floats (fallback only)

    int B    = in_sizes[0] / (CH * PLANE);        // 32
    int nblk = (B * CH) / PPB;                    // 512

    void* args[] = {(void*)&x, (void*)&conv_w, (void*)&fc1_w, (void*)&fc1_b,
                    (void*)&fc2_w, (void*)&fc2_b, (void*)&g, (void*)&out};
    hipError_t e = hipLaunchCooperativeKernel((const void*)fused_kernel, dim3(nblk),
                                              dim3(256), args, 0, stream);
    if (e != hipSuccess) {
        // cooperative launch refused (size check / unsupported) -> proven 3-kernel path
        gap_kernel <<<B * CH, 256, 0, stream>>>(x, g);
        attn_kernel<<<B, 64, 0, stream>>>(g, fc1_w, fc1_b, fc2_w, fc2_b, attn);
        dwconv_kernel<<<B * CH, 256, 0, stream>>>(x, conv_w, attn, out);
    }
}